// Round 6
// baseline (526.831 us; speedup 1.0000x reference)
//
#include <hip/hip_runtime.h>
#include <hip/hip_bf16.h>

// ---------------------------------------------------------------------------
// GAT (2-layer, PyG-style) on MI355X.
// R6: 3-stage decoupled pointer-chase pipeline in both agg kernels (index
//     prefetched a full iteration before its dependent row loads issue);
//     agg_l2 -> 8 edges/wave; dispatch count 17->10 (k_flag/k_convert gone:
//     per-block int64 detect + direct eix reads; 1-block scan; weight prep
//     folded into histogram kernel; single memset).
// ---------------------------------------------------------------------------

typedef __attribute__((ext_vector_type(8)))  __bf16          bf16x8;
typedef __attribute__((ext_vector_type(8)))  unsigned short  ushort8;
typedef __attribute__((ext_vector_type(16))) float           f32x16;

#define NEG_SLOPE 0.2f
#define EPS_GAT 1e-16f

static __device__ __forceinline__ float lrelu(float x) {
    return x > 0.0f ? x : NEG_SLOPE * x;
}
static __device__ __forceinline__ unsigned short f2bf(float f) {
    unsigned u = __float_as_uint(f);
    return (unsigned short)((u + 0x7fffu + ((u >> 16) & 1u)) >> 16);
}
static __device__ __forceinline__ float bf2f(unsigned short v) {
    return __uint_as_float(((unsigned)v) << 16);
}
// ordered-uint encoding for float atomicMax; enc(x)>0 for finite x, so
// memset-0 init acts as -inf.
static __device__ __forceinline__ unsigned encf(float x) {
    unsigned u = __float_as_uint(x);
    return (u >> 31) ? ~u : (u | 0x80000000u);
}
static __device__ __forceinline__ float decf(unsigned e) {
    unsigned u = (e >> 31) ? (e & 0x7fffffffu) : ~e;
    return __uint_as_float(u);
}

// --------------- histogram (direct eix, per-block dtype detect) ------------
// Blocks [0,EB): edge dst histogram. Blocks [EB, EB+WB): weight transpose.
// int64 input => every odd 32-bit word is a zero high word. int32 => odd
// words are random node ids; P(256 samples all zero) ~ (1/N)^k ~ 0.
__global__ void k_hist_w(const void* __restrict__ eix, int* __restrict__ counts,
                         int E, int EB,
                         const float* __restrict__ W1, const float* __restrict__ W2,
                         unsigned short* __restrict__ w1t, unsigned short* __restrict__ w2t) {
    int b = blockIdx.x;
    if (b < EB) {
        int i = b * 256 + threadIdx.x;
        unsigned w = ((const unsigned*)eix)[2 * min(i, E - 1) + 1];
        bool is64 = (__syncthreads_or((int)(w != 0u)) == 0);
        if (i < E) {
            int d = is64 ? (int)((const long long*)eix)[E + i]
                         : ((const int*)eix)[E + i];
            atomicAdd(&counts[d], 1);
        }
    } else {
        int t = (b - EB) * 256 + threadIdx.x;
        if (t < 512 * 256) {
            int k = t >> 8, m = t & 255;
            w1t[m * 512 + k] = f2bf(W1[t]);
        } else {
            int u = t - 512 * 256;
            if (u < 256 * 64) {
                int k = u >> 6, m = u & 63;
                w2t[m * 256 + k] = f2bf(W2[u]);
            }
        }
    }
}

// --------------------- CSR scan: one block, 1024 threads -------------------
__global__ __launch_bounds__(1024) void k_scan(const int* __restrict__ counts,
                                               int* __restrict__ rowp,
                                               int* __restrict__ cursor, int N) {
    __shared__ int sums[1024];
    int tid = threadIdx.x;
    int chunk = (N + 1023) >> 10;
    int b = tid * chunk;
    int e = b + chunk; if (e > N) e = N;
    int s = 0;
    for (int i = b; i < e; ++i) s += counts[i];
    sums[tid] = s;
    __syncthreads();
    for (int off = 1; off < 1024; off <<= 1) {
        int v = (tid >= off) ? sums[tid - off] : 0;
        __syncthreads();
        sums[tid] += v;
        __syncthreads();
    }
    int run = (tid > 0) ? sums[tid - 1] : 0;
    for (int i = b; i < e; ++i) {
        rowp[i] = run;
        cursor[i] = run;
        run += counts[i];
    }
    if (tid == 1023) rowp[N] = sums[1023];
}

// ------------------------ fill (direct eix reads) --------------------------
__global__ void k_fill(const void* __restrict__ eix, int* __restrict__ cursor,
                       int* __restrict__ ssrc, int E) {
    int i = blockIdx.x * 256 + threadIdx.x;
    unsigned w = ((const unsigned*)eix)[2 * min(i, E - 1) + 1];
    bool is64 = (__syncthreads_or((int)(w != 0u)) == 0);
    if (i >= E) return;
    int s, d;
    if (is64) {
        s = (int)((const long long*)eix)[i];
        d = (int)((const long long*)eix)[E + i];
    } else {
        s = ((const int*)eix)[i];
        d = ((const int*)eix)[E + i];
    }
    int pos = atomicAdd(&cursor[d], 1);
    ssrc[pos] = s;
}

// ------------------------------- bf16 GEMM ---------------------------------
template <int BM, int BN, int NT, bool AF32, bool OUTBF>
__global__ __launch_bounds__(NT) void k_gemm(const void* __restrict__ Ain,
                                             const unsigned short* __restrict__ Bt,
                                             void* __restrict__ Cout, int Nrows, int K) {
    constexpr int LD = 40;
    __shared__ __align__(16) unsigned short As[BM * LD];
    __shared__ __align__(16) unsigned short Bs[BN * LD];
    const int tid = threadIdx.x;
    const int blockRow = blockIdx.x * BM;
    const int wave = tid >> 6, lane = tid & 63;
    constexpr int WR = BM / 64;
    const int wr = wave % WR, wc = wave / WR;
    const int m = lane & 31;
    const int ksel = (lane >> 5) * 8;

    f32x16 acc00{}, acc01{}, acc10{}, acc11{};

    for (int kt = 0; kt < K; kt += 32) {
        if constexpr (AF32) {
            const float* A = (const float*)Ain;
            for (int idx = tid; idx < BM * 4; idx += NT) {
                int r = idx >> 2, kc = (idx & 3) * 8;
                int grow = blockRow + r;
                union { ushort8 u; __hip_bfloat162 h[4]; } cv;
                if (grow < Nrows) {
                    const float* ap = A + (size_t)grow * K + kt + kc;
                    float4 x0 = *(const float4*)ap;
                    float4 x1 = *(const float4*)(ap + 4);
                    cv.h[0] = __float22bfloat162_rn(make_float2(x0.x, x0.y));
                    cv.h[1] = __float22bfloat162_rn(make_float2(x0.z, x0.w));
                    cv.h[2] = __float22bfloat162_rn(make_float2(x1.x, x1.y));
                    cv.h[3] = __float22bfloat162_rn(make_float2(x1.z, x1.w));
                } else {
                    cv.u = ushort8{};
                }
                *(ushort8*)&As[r * LD + kc] = cv.u;
            }
        } else {
            const unsigned short* A = (const unsigned short*)Ain;
            for (int idx = tid; idx < BM * 4; idx += NT) {
                int r = idx >> 2, kc = (idx & 3) * 8;
                int grow = blockRow + r;
                ushort8 o{};
                if (grow < Nrows) o = *(const ushort8*)(A + (size_t)grow * K + kt + kc);
                *(ushort8*)&As[r * LD + kc] = o;
            }
        }
        for (int idx = tid; idx < BN * 4; idx += NT) {
            int r = idx >> 2, kc = (idx & 3) * 8;
            *(ushort8*)&Bs[r * LD + kc] = *(const ushort8*)(Bt + (size_t)r * K + kt + kc);
        }
        __syncthreads();

        #pragma unroll
        for (int kk = 0; kk < 32; kk += 16) {
            bf16x8 a0 = *(const bf16x8*)&As[(wr * 64 +      m) * LD + kk + ksel];
            bf16x8 a1 = *(const bf16x8*)&As[(wr * 64 + 32 + m) * LD + kk + ksel];
            bf16x8 b0 = *(const bf16x8*)&Bs[(wc * 64 +      m) * LD + kk + ksel];
            bf16x8 b1 = *(const bf16x8*)&Bs[(wc * 64 + 32 + m) * LD + kk + ksel];
            acc00 = __builtin_amdgcn_mfma_f32_32x32x16_bf16(a0, b0, acc00, 0, 0, 0);
            acc01 = __builtin_amdgcn_mfma_f32_32x32x16_bf16(a0, b1, acc01, 0, 0, 0);
            acc10 = __builtin_amdgcn_mfma_f32_32x32x16_bf16(a1, b0, acc10, 0, 0, 0);
            acc11 = __builtin_amdgcn_mfma_f32_32x32x16_bf16(a1, b1, acc11, 0, 0, 0);
        }
        __syncthreads();
    }

    const int dcol = wc * 64 + (lane & 31);
    const int dquad = 4 * (lane >> 5);
    auto store_tile = [&](const f32x16& a, int rt, int ct) {
        #pragma unroll
        for (int r = 0; r < 16; ++r) {
            int row = blockRow + wr * 64 + rt * 32 + (r & 3) + 8 * (r >> 2) + dquad;
            if (row < Nrows) {
                size_t off = (size_t)row * BN + dcol + ct * 32;
                if constexpr (OUTBF) ((unsigned short*)Cout)[off] = f2bf(a[r]);
                else                 ((float*)Cout)[off] = a[r];
            }
        }
    };
    store_tile(acc00, 0, 0); store_tile(acc01, 0, 1);
    store_tile(acc10, 1, 0); store_tile(acc11, 1, 1);
}

// ----------- attention logits + global head max (atomicMax enc) ------------
__global__ void k_alpha(const unsigned short* __restrict__ xw, const float* __restrict__ a_s,
                        const float* __restrict__ a_d, float* __restrict__ os,
                        float* __restrict__ od, unsigned* __restrict__ Menc,
                        int NH, int H, int C) {
    __shared__ float red[256];
    int t = blockIdx.x * 256 + threadIdx.x;
    float s = -1e30f, d = 0.f;
    if (t < NH) {
        int n = t / H, h = t - n * H;
        const unsigned short* row = xw + (size_t)n * H * C + h * C;
        s = 0.f;
        for (int c = 0; c < C; c += 8) {
            ushort8 v = *(const ushort8*)(row + c);
            #pragma unroll
            for (int q = 0; q < 8; ++q) {
                float f = bf2f(v[q]);
                s += f * a_s[h * C + c + q];
                d += f * a_d[h * C + c + q];
            }
        }
        os[t] = s; od[t] = d;
    }
    red[threadIdx.x] = s;
    __syncthreads();
    for (int off = 128; off >= H; off >>= 1) {
        if (threadIdx.x < off) red[threadIdx.x] = fmaxf(red[threadIdx.x], red[threadIdx.x + off]);
        __syncthreads();
    }
    if ((int)threadIdx.x < H) atomicMax(&Menc[threadIdx.x], encf(red[threadIdx.x]));
}

// ---- layer 1: 4 edges/wave, 3-stage decoupled pointer-chase pipeline ------
// g = lane>>4 picks edge of quad; q = lane&15 holds features [q*16, q*16+16)
__global__ __launch_bounds__(256) void k_agg_l1(
        const unsigned short* __restrict__ xw1, const float* __restrict__ asrc,
        const float* __restrict__ adst, const unsigned* __restrict__ Menc,
        const float* __restrict__ b1, const int* __restrict__ rp,
        const int* __restrict__ ssrc, unsigned short* __restrict__ hbf, int N) {
    int wid = (blockIdx.x * 256 + threadIdx.x) >> 6;
    if (wid >= N) return;
    int lane = threadIdx.x & 63;
    int g  = lane >> 4;
    int q  = lane & 15;
    int f0 = q * 16;
    int h  = q >> 1;
    int ih = wid * 8 + h;
    float ad = adst[ih];
    float m  = lrelu(decf(Menc[h]) + ad);   // >= all edge logits (lrelu monotone)
    float acc[16];
    float s;
    {   // self loop counted on group 0 only
        float w = (g == 0) ? __expf(lrelu(asrc[ih] + ad) - m) : 0.0f;
        const unsigned short* pr = xw1 + (size_t)wid * 256 + f0;
        ushort8 lo = *(const ushort8*)pr;
        ushort8 hi = *(const ushort8*)(pr + 8);
        s = w;
        #pragma unroll
        for (int i = 0; i < 8; ++i) { acc[i] = w * bf2f(lo[i]); acc[8 + i] = w * bf2f(hi[i]); }
    }
    int e0 = rp[wid], e1 = rp[wid + 1];
    if (e0 < e1) {
        // stage A: data resident; stage B: j resident, data in flight;
        // stage C: j in flight.  No same-iteration chained waits.
        int eA = e0;
        bool vA = eA + g < e1;
        int jA = ssrc[min(eA + g, e1 - 1)];
        float asA = asrc[jA * 8 + h];
        const unsigned short* pA = xw1 + (size_t)jA * 256 + f0;
        ushort8 loA = *(const ushort8*)pA;
        ushort8 hiA = *(const ushort8*)(pA + 8);
        int eB = e0 + 4;
        bool hasB = eB < e1;
        bool vB = false; int jB = 0;
        if (hasB) { vB = eB + g < e1; jB = ssrc[min(eB + g, e1 - 1)]; }
        int eC = e0 + 8;
        while (true) {
            // issue stage-C index load
            bool hasC = eC < e1;
            bool vC = false; int jC = 0;
            if (hasC) { vC = eC + g < e1; jC = ssrc[min(eC + g, e1 - 1)]; }
            // issue stage-B data loads (jB was fetched last iteration)
            float asB = 0.f; ushort8 loB{}, hiB{};
            if (hasB) {
                asB = asrc[jB * 8 + h];
                const unsigned short* pB = xw1 + (size_t)jB * 256 + f0;
                loB = *(const ushort8*)pB;
                hiB = *(const ushort8*)(pB + 8);
            }
            // consume stage A (its loads were issued last iteration)
            float w = vA ? __expf(lrelu(asA + ad) - m) : 0.0f;
            s += w;
            #pragma unroll
            for (int i = 0; i < 8; ++i) {
                acc[i]     += w * bf2f(loA[i]);
                acc[8 + i] += w * bf2f(hiA[i]);
            }
            if (!hasB) break;
            vA = vB; asA = asB; loA = loB; hiA = hiB;
            jB = jC; vB = vC; hasB = hasC;
            eC += 4;
        }
    }
    // combine the 4 edge-groups
    s += __shfl_xor(s, 16, 64);
    s += __shfl_xor(s, 32, 64);
    #pragma unroll
    for (int i = 0; i < 16; ++i) {
        acc[i] += __shfl_xor(acc[i], 16, 64);
        acc[i] += __shfl_xor(acc[i], 32, 64);
    }
    float inv = 1.0f / (s + EPS_GAT);
    // group g writes features [f0 + g*4, f0 + g*4 + 4)
    int fw = f0 + g * 4;
    ushort4 o;
    #pragma unroll
    for (int i = 0; i < 4; ++i) {
        float v = acc[g * 4 + i] * inv + b1[fw + i];
        v = v > 0.f ? v : expm1f(v);
        ((unsigned short*)&o)[i] = f2bf(v);
    }
    *(ushort4*)(hbf + (size_t)wid * 256 + fw) = o;
}

// ---- layer 2: 8 edges/wave, 3-stage pipeline + fused log_softmax ----------
// g = lane>>3 picks edge of octet; q = lane&7 holds classes [q*8, q*8+8)
__global__ __launch_bounds__(256) void k_agg_l2(
        const unsigned short* __restrict__ xw2, const float* __restrict__ asrc,
        const float* __restrict__ adst, const unsigned* __restrict__ Menc,
        const float* __restrict__ b2, const int* __restrict__ rp,
        const int* __restrict__ ssrc, float* __restrict__ out, int N) {
    int wid = (blockIdx.x * 256 + threadIdx.x) >> 6;
    if (wid >= N) return;
    int lane = threadIdx.x & 63;
    int g  = lane >> 3;
    int q  = lane & 7;
    int f0 = q * 8;
    float ad = adst[wid];
    float m = lrelu(decf(Menc[0]) + ad);
    float acc[8];
    float s;
    {   // self loop counted on group 0 only
        float w = (g == 0) ? __expf(lrelu(asrc[wid] + ad) - m) : 0.0f;
        ushort8 xv = *(const ushort8*)(xw2 + (size_t)wid * 64 + f0);
        s = w;
        #pragma unroll
        for (int i = 0; i < 8; ++i) acc[i] = w * bf2f(xv[i]);
    }
    int e0 = rp[wid], e1 = rp[wid + 1];
    if (e0 < e1) {
        int eA = e0;
        bool vA = eA + g < e1;
        int jA = ssrc[min(eA + g, e1 - 1)];
        float asA = asrc[jA];
        ushort8 xvA = *(const ushort8*)(xw2 + (size_t)jA * 64 + f0);
        int eB = e0 + 8;
        bool hasB = eB < e1;
        bool vB = false; int jB = 0;
        if (hasB) { vB = eB + g < e1; jB = ssrc[min(eB + g, e1 - 1)]; }
        int eC = e0 + 16;
        while (true) {
            bool hasC = eC < e1;
            bool vC = false; int jC = 0;
            if (hasC) { vC = eC + g < e1; jC = ssrc[min(eC + g, e1 - 1)]; }
            float asB = 0.f; ushort8 xvB{};
            if (hasB) {
                asB = asrc[jB];
                xvB = *(const ushort8*)(xw2 + (size_t)jB * 64 + f0);
            }
            float w = vA ? __expf(lrelu(asA + ad) - m) : 0.0f;
            s += w;
            #pragma unroll
            for (int i = 0; i < 8; ++i) acc[i] += w * bf2f(xvA[i]);
            if (!hasB) break;
            vA = vB; asA = asB; xvA = xvB;
            jB = jC; vB = vC; hasB = hasC;
            eC += 8;
        }
    }
    // combine the 8 edge-groups (group id in lane bits 3..5)
    s += __shfl_xor(s, 8, 64);
    s += __shfl_xor(s, 16, 64);
    s += __shfl_xor(s, 32, 64);
    #pragma unroll
    for (int i = 0; i < 8; ++i) {
        acc[i] += __shfl_xor(acc[i], 8, 64);
        acc[i] += __shfl_xor(acc[i], 16, 64);
        acc[i] += __shfl_xor(acc[i], 32, 64);
    }
    float inv = 1.0f / (s + EPS_GAT);
    float val[8];
    float mx = -1e30f;
    #pragma unroll
    for (int i = 0; i < 8; ++i) {
        val[i] = acc[i] * inv + b2[f0 + i];
        mx = fmaxf(mx, val[i]);
    }
    // class reduce across q lanes (bits 0..2)
    #pragma unroll
    for (int off = 4; off > 0; off >>= 1) mx = fmaxf(mx, __shfl_xor(mx, off, 64));
    float sm = 0.f;
    #pragma unroll
    for (int i = 0; i < 8; ++i) sm += __expf(val[i] - mx);
    #pragma unroll
    for (int off = 4; off > 0; off >>= 1) sm += __shfl_xor(sm, off, 64);
    float lse = mx + logf(sm);
    if (g == 0) {
        float4 o0 = make_float4(val[0] - lse, val[1] - lse, val[2] - lse, val[3] - lse);
        float4 o1 = make_float4(val[4] - lse, val[5] - lse, val[6] - lse, val[7] - lse);
        *(float4*)(out + (size_t)wid * 64 + f0)     = o0;
        *(float4*)(out + (size_t)wid * 64 + f0 + 4) = o1;
    }
}

// ------------------------------- launcher ----------------------------------
static inline int cdiv(int a, int b) { return (a + b - 1) / b; }

extern "C" void kernel_launch(void* const* d_in, const int* in_sizes, int n_in,
                              void* d_out, int out_size, void* d_ws, size_t ws_size,
                              hipStream_t stream) {
    const float* x   = (const float*)d_in[0];
    const void*  eix = d_in[1];
    const float* W1  = (const float*)d_in[2];
    const float* as1 = (const float*)d_in[3];
    const float* ad1 = (const float*)d_in[4];
    const float* b1  = (const float*)d_in[5];
    const float* W2  = (const float*)d_in[6];
    const float* as2 = (const float*)d_in[7];
    const float* ad2 = (const float*)d_in[8];
    const float* b2  = (const float*)d_in[9];
    float* out = (float*)d_out;

    const int N = in_sizes[0] / 512;
    const int E = in_sizes[1] / 2;
    const int EB = cdiv(E, 256);
    const int WB = cdiv(512 * 256 + 256 * 64, 256);
    const int NB1 = cdiv(N * 8, 256);
    const int NB2 = cdiv(N, 256);
    (void)n_in; (void)out_size; (void)ws_size;

    char* base = (char*)d_ws;
    size_t o = 0;
    auto alloc = [&](size_t bytes) -> char* {
        o = (o + 255) & ~(size_t)255;
        char* p = base + o;
        o += bytes;
        return p;
    };
    unsigned short* xw1b  = (unsigned short*)alloc((size_t)N * 256 * 2);
    unsigned short* hbf   = (unsigned short*)alloc((size_t)N * 256 * 2);
    unsigned short* xw2b  = (unsigned short*)alloc((size_t)N * 64 * 2);
    float*          asrc1 = (float*)alloc((size_t)N * 8 * 4);
    float*          adst1 = (float*)alloc((size_t)N * 8 * 4);
    float*          asrc2 = (float*)alloc((size_t)N * 4);
    float*          adst2 = (float*)alloc((size_t)N * 4);
    // zero region: Menc + counts contiguous, one memset
    size_t zero_begin = (o + 255) & ~(size_t)255;
    unsigned*       Menc  = (unsigned*)alloc(16 * 4);   // [0..7]=L1 heads, [8]=L2
    int*            counts= (int*)alloc((size_t)N * 4);
    size_t zero_end = o;
    int*            cursor= (int*)alloc((size_t)N * 4);
    int*            rowp  = (int*)alloc((size_t)(N + 1) * 4);
    unsigned short* w1t   = (unsigned short*)alloc(512 * 256 * 2);
    unsigned short* w2t   = (unsigned short*)alloc(256 * 64 * 2);
    int*            ssrc  = (int*)alloc((size_t)E * 4);

    hipMemsetAsync(base + zero_begin, 0, zero_end - zero_begin, stream);

    // CSR build (3 kernels) + weight prep folded into histogram grid
    k_hist_w<<<EB + WB, 256, 0, stream>>>(eix, counts, E, EB, W1, W2, w1t, w2t);
    k_scan<<<1, 1024, 0, stream>>>(counts, rowp, cursor, N);
    k_fill<<<EB, 256, 0, stream>>>(eix, cursor, ssrc, E);

    // layer 1
    k_gemm<128, 256, 512, true, true><<<cdiv(N, 128), 512, 0, stream>>>(x, w1t, xw1b, N, 512);
    k_alpha<<<NB1, 256, 0, stream>>>(xw1b, as1, ad1, asrc1, adst1, Menc, N * 8, 8, 32);
    k_agg_l1<<<cdiv(N * 64, 256), 256, 0, stream>>>(xw1b, asrc1, adst1, Menc, b1,
                                                    rowp, ssrc, hbf, N);
    // layer 2
    k_gemm<256, 64, 256, false, true><<<cdiv(N, 256), 256, 0, stream>>>(hbf, w2t, xw2b, N, 256);
    k_alpha<<<NB2, 256, 0, stream>>>(xw2b, as2, ad2, asrc2, adst2, Menc + 8, N, 1, 64);
    k_agg_l2<<<cdiv(N * 64, 256), 256, 0, stream>>>(xw2b, asrc2, adst2, Menc + 8, b2,
                                                    rowp, ssrc, out, N);
}

// Round 7
// 420.963 us; speedup vs baseline: 1.2515x; 1.2515x over previous
//
#include <hip/hip_runtime.h>
#include <hip/hip_bf16.h>

// ---------------------------------------------------------------------------
// GAT (2-layer, PyG-style) on MI355X.
// R7: restore hierarchical CSR scan (R6's single-block scan cost 110us:
//     occupancy 0.14%, latency-serialized). Keep R6's direct-eix hist/fill,
//     folded weight prep, single memset, 3-stage pipelined agg kernels.
// ---------------------------------------------------------------------------

typedef __attribute__((ext_vector_type(8)))  __bf16          bf16x8;
typedef __attribute__((ext_vector_type(8)))  unsigned short  ushort8;
typedef __attribute__((ext_vector_type(16))) float           f32x16;

#define NEG_SLOPE 0.2f
#define EPS_GAT 1e-16f

static __device__ __forceinline__ float lrelu(float x) {
    return x > 0.0f ? x : NEG_SLOPE * x;
}
static __device__ __forceinline__ unsigned short f2bf(float f) {
    unsigned u = __float_as_uint(f);
    return (unsigned short)((u + 0x7fffu + ((u >> 16) & 1u)) >> 16);
}
static __device__ __forceinline__ float bf2f(unsigned short v) {
    return __uint_as_float(((unsigned)v) << 16);
}
// ordered-uint encoding for float atomicMax; enc(x)>0 for finite x, so
// memset-0 init acts as -inf.
static __device__ __forceinline__ unsigned encf(float x) {
    unsigned u = __float_as_uint(x);
    return (u >> 31) ? ~u : (u | 0x80000000u);
}
static __device__ __forceinline__ float decf(unsigned e) {
    unsigned u = (e >> 31) ? (e & 0x7fffffffu) : ~e;
    return __uint_as_float(u);
}

// --------------- histogram (direct eix, per-block dtype detect) ------------
// Blocks [0,EB): edge dst histogram. Blocks [EB, EB+WB): weight transpose.
// int64 input => every odd 32-bit word is a zero high word. int32 => odd
// words are random node ids; P(256 samples all zero) ~ (1/N)^256 ~ 0.
__global__ void k_hist_w(const void* __restrict__ eix, int* __restrict__ counts,
                         int E, int EB,
                         const float* __restrict__ W1, const float* __restrict__ W2,
                         unsigned short* __restrict__ w1t, unsigned short* __restrict__ w2t) {
    int b = blockIdx.x;
    if (b < EB) {
        int i = b * 256 + threadIdx.x;
        unsigned w = ((const unsigned*)eix)[2 * min(i, E - 1) + 1];
        bool is64 = (__syncthreads_or((int)(w != 0u)) == 0);
        if (i < E) {
            int d = is64 ? (int)((const long long*)eix)[E + i]
                         : ((const int*)eix)[E + i];
            atomicAdd(&counts[d], 1);
        }
    } else {
        int t = (b - EB) * 256 + threadIdx.x;
        if (t < 512 * 256) {
            int k = t >> 8, m = t & 255;
            w1t[m * 512 + k] = f2bf(W1[t]);
        } else {
            int u = t - 512 * 256;
            if (u < 256 * 64) {
                int k = u >> 6, m = u & 63;
                w2t[m * 256 + k] = f2bf(W2[u]);
            }
        }
    }
}

// -------------------- hierarchical CSR scan (3 kernels) --------------------
__global__ void k_scan1(const int* __restrict__ counts, int* __restrict__ rowp,
                        int* __restrict__ bsum, int N) {
    __shared__ int s[256];
    int t = threadIdx.x, i = blockIdx.x * 256 + t;
    int v = (i < N) ? counts[i] : 0;
    s[t] = v;
    __syncthreads();
    for (int off = 1; off < 256; off <<= 1) {
        int u = (t >= off) ? s[t - off] : 0;
        __syncthreads();
        s[t] += u;
        __syncthreads();
    }
    if (i < N) rowp[i] = s[t] - v;          // exclusive within block
    if (t == 255) bsum[blockIdx.x] = s[255];
}

__global__ void k_scan2(const int* __restrict__ bsum, int* __restrict__ boff,
                        int* __restrict__ rowp_last, int NB) {
    __shared__ int s[256];
    int t = threadIdx.x;
    int v = (t < NB) ? bsum[t] : 0;
    s[t] = v;
    __syncthreads();
    for (int off = 1; off < 256; off <<= 1) {
        int u = (t >= off) ? s[t - off] : 0;
        __syncthreads();
        s[t] += u;
        __syncthreads();
    }
    if (t < NB) boff[t] = s[t] - v;
    if (t == 255) *rowp_last = s[255];      // == E
}

__global__ void k_scan3(int* __restrict__ rowp, int* __restrict__ cursor,
                        const int* __restrict__ boff, int N) {
    int i = blockIdx.x * 256 + threadIdx.x;
    if (i < N) {
        int r = rowp[i] + boff[blockIdx.x];
        rowp[i] = r;
        cursor[i] = r;
    }
}

// ------------------------ fill (direct eix reads) --------------------------
__global__ void k_fill(const void* __restrict__ eix, int* __restrict__ cursor,
                       int* __restrict__ ssrc, int E) {
    int i = blockIdx.x * 256 + threadIdx.x;
    unsigned w = ((const unsigned*)eix)[2 * min(i, E - 1) + 1];
    bool is64 = (__syncthreads_or((int)(w != 0u)) == 0);
    if (i >= E) return;
    int s, d;
    if (is64) {
        s = (int)((const long long*)eix)[i];
        d = (int)((const long long*)eix)[E + i];
    } else {
        s = ((const int*)eix)[i];
        d = ((const int*)eix)[E + i];
    }
    int pos = atomicAdd(&cursor[d], 1);
    ssrc[pos] = s;
}

// ------------------------------- bf16 GEMM ---------------------------------
template <int BM, int BN, int NT, bool AF32, bool OUTBF>
__global__ __launch_bounds__(NT) void k_gemm(const void* __restrict__ Ain,
                                             const unsigned short* __restrict__ Bt,
                                             void* __restrict__ Cout, int Nrows, int K) {
    constexpr int LD = 40;
    __shared__ __align__(16) unsigned short As[BM * LD];
    __shared__ __align__(16) unsigned short Bs[BN * LD];
    const int tid = threadIdx.x;
    const int blockRow = blockIdx.x * BM;
    const int wave = tid >> 6, lane = tid & 63;
    constexpr int WR = BM / 64;
    const int wr = wave % WR, wc = wave / WR;
    const int m = lane & 31;
    const int ksel = (lane >> 5) * 8;

    f32x16 acc00{}, acc01{}, acc10{}, acc11{};

    for (int kt = 0; kt < K; kt += 32) {
        if constexpr (AF32) {
            const float* A = (const float*)Ain;
            for (int idx = tid; idx < BM * 4; idx += NT) {
                int r = idx >> 2, kc = (idx & 3) * 8;
                int grow = blockRow + r;
                union { ushort8 u; __hip_bfloat162 h[4]; } cv;
                if (grow < Nrows) {
                    const float* ap = A + (size_t)grow * K + kt + kc;
                    float4 x0 = *(const float4*)ap;
                    float4 x1 = *(const float4*)(ap + 4);
                    cv.h[0] = __float22bfloat162_rn(make_float2(x0.x, x0.y));
                    cv.h[1] = __float22bfloat162_rn(make_float2(x0.z, x0.w));
                    cv.h[2] = __float22bfloat162_rn(make_float2(x1.x, x1.y));
                    cv.h[3] = __float22bfloat162_rn(make_float2(x1.z, x1.w));
                } else {
                    cv.u = ushort8{};
                }
                *(ushort8*)&As[r * LD + kc] = cv.u;
            }
        } else {
            const unsigned short* A = (const unsigned short*)Ain;
            for (int idx = tid; idx < BM * 4; idx += NT) {
                int r = idx >> 2, kc = (idx & 3) * 8;
                int grow = blockRow + r;
                ushort8 o{};
                if (grow < Nrows) o = *(const ushort8*)(A + (size_t)grow * K + kt + kc);
                *(ushort8*)&As[r * LD + kc] = o;
            }
        }
        for (int idx = tid; idx < BN * 4; idx += NT) {
            int r = idx >> 2, kc = (idx & 3) * 8;
            *(ushort8*)&Bs[r * LD + kc] = *(const ushort8*)(Bt + (size_t)r * K + kt + kc);
        }
        __syncthreads();

        #pragma unroll
        for (int kk = 0; kk < 32; kk += 16) {
            bf16x8 a0 = *(const bf16x8*)&As[(wr * 64 +      m) * LD + kk + ksel];
            bf16x8 a1 = *(const bf16x8*)&As[(wr * 64 + 32 + m) * LD + kk + ksel];
            bf16x8 b0 = *(const bf16x8*)&Bs[(wc * 64 +      m) * LD + kk + ksel];
            bf16x8 b1 = *(const bf16x8*)&Bs[(wc * 64 + 32 + m) * LD + kk + ksel];
            acc00 = __builtin_amdgcn_mfma_f32_32x32x16_bf16(a0, b0, acc00, 0, 0, 0);
            acc01 = __builtin_amdgcn_mfma_f32_32x32x16_bf16(a0, b1, acc01, 0, 0, 0);
            acc10 = __builtin_amdgcn_mfma_f32_32x32x16_bf16(a1, b0, acc10, 0, 0, 0);
            acc11 = __builtin_amdgcn_mfma_f32_32x32x16_bf16(a1, b1, acc11, 0, 0, 0);
        }
        __syncthreads();
    }

    const int dcol = wc * 64 + (lane & 31);
    const int dquad = 4 * (lane >> 5);
    auto store_tile = [&](const f32x16& a, int rt, int ct) {
        #pragma unroll
        for (int r = 0; r < 16; ++r) {
            int row = blockRow + wr * 64 + rt * 32 + (r & 3) + 8 * (r >> 2) + dquad;
            if (row < Nrows) {
                size_t off = (size_t)row * BN + dcol + ct * 32;
                if constexpr (OUTBF) ((unsigned short*)Cout)[off] = f2bf(a[r]);
                else                 ((float*)Cout)[off] = a[r];
            }
        }
    };
    store_tile(acc00, 0, 0); store_tile(acc01, 0, 1);
    store_tile(acc10, 1, 0); store_tile(acc11, 1, 1);
}

// ----------- attention logits + global head max (atomicMax enc) ------------
__global__ void k_alpha(const unsigned short* __restrict__ xw, const float* __restrict__ a_s,
                        const float* __restrict__ a_d, float* __restrict__ os,
                        float* __restrict__ od, unsigned* __restrict__ Menc,
                        int NH, int H, int C) {
    __shared__ float red[256];
    int t = blockIdx.x * 256 + threadIdx.x;
    float s = -1e30f, d = 0.f;
    if (t < NH) {
        int n = t / H, h = t - n * H;
        const unsigned short* row = xw + (size_t)n * H * C + h * C;
        s = 0.f;
        for (int c = 0; c < C; c += 8) {
            ushort8 v = *(const ushort8*)(row + c);
            #pragma unroll
            for (int q = 0; q < 8; ++q) {
                float f = bf2f(v[q]);
                s += f * a_s[h * C + c + q];
                d += f * a_d[h * C + c + q];
            }
        }
        os[t] = s; od[t] = d;
    }
    red[threadIdx.x] = s;
    __syncthreads();
    for (int off = 128; off >= H; off >>= 1) {
        if (threadIdx.x < off) red[threadIdx.x] = fmaxf(red[threadIdx.x], red[threadIdx.x + off]);
        __syncthreads();
    }
    if ((int)threadIdx.x < H) atomicMax(&Menc[threadIdx.x], encf(red[threadIdx.x]));
}

// ---- layer 1: 4 edges/wave, 3-stage decoupled pointer-chase pipeline ------
// g = lane>>4 picks edge of quad; q = lane&15 holds features [q*16, q*16+16)
__global__ __launch_bounds__(256) void k_agg_l1(
        const unsigned short* __restrict__ xw1, const float* __restrict__ asrc,
        const float* __restrict__ adst, const unsigned* __restrict__ Menc,
        const float* __restrict__ b1, const int* __restrict__ rp,
        const int* __restrict__ ssrc, unsigned short* __restrict__ hbf, int N) {
    int wid = (blockIdx.x * 256 + threadIdx.x) >> 6;
    if (wid >= N) return;
    int lane = threadIdx.x & 63;
    int g  = lane >> 4;
    int q  = lane & 15;
    int f0 = q * 16;
    int h  = q >> 1;
    int ih = wid * 8 + h;
    float ad = adst[ih];
    float m  = lrelu(decf(Menc[h]) + ad);   // >= all edge logits (lrelu monotone)
    float acc[16];
    float s;
    {   // self loop counted on group 0 only
        float w = (g == 0) ? __expf(lrelu(asrc[ih] + ad) - m) : 0.0f;
        const unsigned short* pr = xw1 + (size_t)wid * 256 + f0;
        ushort8 lo = *(const ushort8*)pr;
        ushort8 hi = *(const ushort8*)(pr + 8);
        s = w;
        #pragma unroll
        for (int i = 0; i < 8; ++i) { acc[i] = w * bf2f(lo[i]); acc[8 + i] = w * bf2f(hi[i]); }
    }
    int e0 = rp[wid], e1 = rp[wid + 1];
    if (e0 < e1) {
        // stage A: data resident; stage B: j resident, data in flight;
        // stage C: j in flight.  No same-iteration chained waits.
        int eA = e0;
        bool vA = eA + g < e1;
        int jA = ssrc[min(eA + g, e1 - 1)];
        float asA = asrc[jA * 8 + h];
        const unsigned short* pA = xw1 + (size_t)jA * 256 + f0;
        ushort8 loA = *(const ushort8*)pA;
        ushort8 hiA = *(const ushort8*)(pA + 8);
        int eB = e0 + 4;
        bool hasB = eB < e1;
        bool vB = false; int jB = 0;
        if (hasB) { vB = eB + g < e1; jB = ssrc[min(eB + g, e1 - 1)]; }
        int eC = e0 + 8;
        while (true) {
            // issue stage-C index load
            bool hasC = eC < e1;
            bool vC = false; int jC = 0;
            if (hasC) { vC = eC + g < e1; jC = ssrc[min(eC + g, e1 - 1)]; }
            // issue stage-B data loads (jB was fetched last iteration)
            float asB = 0.f; ushort8 loB{}, hiB{};
            if (hasB) {
                asB = asrc[jB * 8 + h];
                const unsigned short* pB = xw1 + (size_t)jB * 256 + f0;
                loB = *(const ushort8*)pB;
                hiB = *(const ushort8*)(pB + 8);
            }
            // consume stage A (its loads were issued last iteration)
            float w = vA ? __expf(lrelu(asA + ad) - m) : 0.0f;
            s += w;
            #pragma unroll
            for (int i = 0; i < 8; ++i) {
                acc[i]     += w * bf2f(loA[i]);
                acc[8 + i] += w * bf2f(hiA[i]);
            }
            if (!hasB) break;
            vA = vB; asA = asB; loA = loB; hiA = hiB;
            jB = jC; vB = vC; hasB = hasC;
            eC += 4;
        }
    }
    // combine the 4 edge-groups
    s += __shfl_xor(s, 16, 64);
    s += __shfl_xor(s, 32, 64);
    #pragma unroll
    for (int i = 0; i < 16; ++i) {
        acc[i] += __shfl_xor(acc[i], 16, 64);
        acc[i] += __shfl_xor(acc[i], 32, 64);
    }
    float inv = 1.0f / (s + EPS_GAT);
    // group g writes features [f0 + g*4, f0 + g*4 + 4)
    int fw = f0 + g * 4;
    ushort4 o;
    #pragma unroll
    for (int i = 0; i < 4; ++i) {
        float v = acc[g * 4 + i] * inv + b1[fw + i];
        v = v > 0.f ? v : expm1f(v);
        ((unsigned short*)&o)[i] = f2bf(v);
    }
    *(ushort4*)(hbf + (size_t)wid * 256 + fw) = o;
}

// ---- layer 2: 8 edges/wave, 3-stage pipeline + fused log_softmax ----------
// g = lane>>3 picks edge of octet; q = lane&7 holds classes [q*8, q*8+8)
__global__ __launch_bounds__(256) void k_agg_l2(
        const unsigned short* __restrict__ xw2, const float* __restrict__ asrc,
        const float* __restrict__ adst, const unsigned* __restrict__ Menc,
        const float* __restrict__ b2, const int* __restrict__ rp,
        const int* __restrict__ ssrc, float* __restrict__ out, int N) {
    int wid = (blockIdx.x * 256 + threadIdx.x) >> 6;
    if (wid >= N) return;
    int lane = threadIdx.x & 63;
    int g  = lane >> 3;
    int q  = lane & 7;
    int f0 = q * 8;
    float ad = adst[wid];
    float m = lrelu(decf(Menc[0]) + ad);
    float acc[8];
    float s;
    {   // self loop counted on group 0 only
        float w = (g == 0) ? __expf(lrelu(asrc[wid] + ad) - m) : 0.0f;
        ushort8 xv = *(const ushort8*)(xw2 + (size_t)wid * 64 + f0);
        s = w;
        #pragma unroll
        for (int i = 0; i < 8; ++i) acc[i] = w * bf2f(xv[i]);
    }
    int e0 = rp[wid], e1 = rp[wid + 1];
    if (e0 < e1) {
        int eA = e0;
        bool vA = eA + g < e1;
        int jA = ssrc[min(eA + g, e1 - 1)];
        float asA = asrc[jA];
        ushort8 xvA = *(const ushort8*)(xw2 + (size_t)jA * 64 + f0);
        int eB = e0 + 8;
        bool hasB = eB < e1;
        bool vB = false; int jB = 0;
        if (hasB) { vB = eB + g < e1; jB = ssrc[min(eB + g, e1 - 1)]; }
        int eC = e0 + 16;
        while (true) {
            bool hasC = eC < e1;
            bool vC = false; int jC = 0;
            if (hasC) { vC = eC + g < e1; jC = ssrc[min(eC + g, e1 - 1)]; }
            float asB = 0.f; ushort8 xvB{};
            if (hasB) {
                asB = asrc[jB];
                xvB = *(const ushort8*)(xw2 + (size_t)jB * 64 + f0);
            }
            float w = vA ? __expf(lrelu(asA + ad) - m) : 0.0f;
            s += w;
            #pragma unroll
            for (int i = 0; i < 8; ++i) acc[i] += w * bf2f(xvA[i]);
            if (!hasB) break;
            vA = vB; asA = asB; xvA = xvB;
            jB = jC; vB = vC; hasB = hasC;
            eC += 8;
        }
    }
    // combine the 8 edge-groups (group id in lane bits 3..5)
    s += __shfl_xor(s, 8, 64);
    s += __shfl_xor(s, 16, 64);
    s += __shfl_xor(s, 32, 64);
    #pragma unroll
    for (int i = 0; i < 8; ++i) {
        acc[i] += __shfl_xor(acc[i], 8, 64);
        acc[i] += __shfl_xor(acc[i], 16, 64);
        acc[i] += __shfl_xor(acc[i], 32, 64);
    }
    float inv = 1.0f / (s + EPS_GAT);
    float val[8];
    float mx = -1e30f;
    #pragma unroll
    for (int i = 0; i < 8; ++i) {
        val[i] = acc[i] * inv + b2[f0 + i];
        mx = fmaxf(mx, val[i]);
    }
    // class reduce across q lanes (bits 0..2)
    #pragma unroll
    for (int off = 4; off > 0; off >>= 1) mx = fmaxf(mx, __shfl_xor(mx, off, 64));
    float sm = 0.f;
    #pragma unroll
    for (int i = 0; i < 8; ++i) sm += __expf(val[i] - mx);
    #pragma unroll
    for (int off = 4; off > 0; off >>= 1) sm += __shfl_xor(sm, off, 64);
    float lse = mx + logf(sm);
    if (g == 0) {
        float4 o0 = make_float4(val[0] - lse, val[1] - lse, val[2] - lse, val[3] - lse);
        float4 o1 = make_float4(val[4] - lse, val[5] - lse, val[6] - lse, val[7] - lse);
        *(float4*)(out + (size_t)wid * 64 + f0)     = o0;
        *(float4*)(out + (size_t)wid * 64 + f0 + 4) = o1;
    }
}

// ------------------------------- launcher ----------------------------------
static inline int cdiv(int a, int b) { return (a + b - 1) / b; }

extern "C" void kernel_launch(void* const* d_in, const int* in_sizes, int n_in,
                              void* d_out, int out_size, void* d_ws, size_t ws_size,
                              hipStream_t stream) {
    const float* x   = (const float*)d_in[0];
    const void*  eix = d_in[1];
    const float* W1  = (const float*)d_in[2];
    const float* as1 = (const float*)d_in[3];
    const float* ad1 = (const float*)d_in[4];
    const float* b1  = (const float*)d_in[5];
    const float* W2  = (const float*)d_in[6];
    const float* as2 = (const float*)d_in[7];
    const float* ad2 = (const float*)d_in[8];
    const float* b2  = (const float*)d_in[9];
    float* out = (float*)d_out;

    const int N = in_sizes[0] / 512;
    const int E = in_sizes[1] / 2;
    const int EB = cdiv(E, 256);
    const int WB = cdiv(512 * 256 + 256 * 64, 256);
    const int NB = cdiv(N, 256);
    const int NB1 = cdiv(N * 8, 256);
    const int NB2 = cdiv(N, 256);
    (void)n_in; (void)out_size; (void)ws_size;

    char* base = (char*)d_ws;
    size_t o = 0;
    auto alloc = [&](size_t bytes) -> char* {
        o = (o + 255) & ~(size_t)255;
        char* p = base + o;
        o += bytes;
        return p;
    };
    unsigned short* xw1b  = (unsigned short*)alloc((size_t)N * 256 * 2);
    unsigned short* hbf   = (unsigned short*)alloc((size_t)N * 256 * 2);
    unsigned short* xw2b  = (unsigned short*)alloc((size_t)N * 64 * 2);
    float*          asrc1 = (float*)alloc((size_t)N * 8 * 4);
    float*          adst1 = (float*)alloc((size_t)N * 8 * 4);
    float*          asrc2 = (float*)alloc((size_t)N * 4);
    float*          adst2 = (float*)alloc((size_t)N * 4);
    // zero region: Menc + counts contiguous, one memset
    size_t zero_begin = (o + 255) & ~(size_t)255;
    unsigned*       Menc  = (unsigned*)alloc(16 * 4);   // [0..7]=L1 heads, [8]=L2
    int*            counts= (int*)alloc((size_t)N * 4);
    size_t zero_end = o;
    int*            cursor= (int*)alloc((size_t)N * 4);
    int*            rowp  = (int*)alloc((size_t)(N + 1) * 4);
    int*            bsum  = (int*)alloc(256 * 4);
    int*            boff  = (int*)alloc(256 * 4);
    unsigned short* w1t   = (unsigned short*)alloc(512 * 256 * 2);
    unsigned short* w2t   = (unsigned short*)alloc(256 * 64 * 2);
    int*            ssrc  = (int*)alloc((size_t)E * 4);

    hipMemsetAsync(base + zero_begin, 0, zero_end - zero_begin, stream);

    // CSR build + weight prep folded into histogram grid
    k_hist_w<<<EB + WB, 256, 0, stream>>>(eix, counts, E, EB, W1, W2, w1t, w2t);
    k_scan1<<<NB, 256, 0, stream>>>(counts, rowp, bsum, N);
    k_scan2<<<1, 256, 0, stream>>>(bsum, boff, rowp + N, NB);
    k_scan3<<<NB, 256, 0, stream>>>(rowp, cursor, boff, N);
    k_fill<<<EB, 256, 0, stream>>>(eix, cursor, ssrc, E);

    // layer 1
    k_gemm<128, 256, 512, true, true><<<cdiv(N, 128), 512, 0, stream>>>(x, w1t, xw1b, N, 512);
    k_alpha<<<NB1, 256, 0, stream>>>(xw1b, as1, ad1, asrc1, adst1, Menc, N * 8, 8, 32);
    k_agg_l1<<<cdiv(N * 64, 256), 256, 0, stream>>>(xw1b, asrc1, adst1, Menc, b1,
                                                    rowp, ssrc, hbf, N);
    // layer 2
    k_gemm<256, 64, 256, false, true><<<cdiv(N, 256), 256, 0, stream>>>(hbf, w2t, xw2b, N, 256);
    k_alpha<<<NB2, 256, 0, stream>>>(xw2b, as2, ad2, asrc2, adst2, Menc + 8, N, 1, 64);
    k_agg_l2<<<cdiv(N * 64, 256), 256, 0, stream>>>(xw2b, asrc2, adst2, Menc + 8, b2,
                                                    rowp, ssrc, out, N);
}